// Round 1
// baseline (540.546 us; speedup 1.0000x reference)
//
#include <hip/hip_runtime.h>
#include <stdint.h>

// Problem constants (from reference): B=8, L=4096, D=1024, S=255
constexpr int kB = 8;
constexpr int kL = 4096;
constexpr int kD = 1024;
constexpr int kS = 255;
constexpr int kM = kB * kL;   // 32768 rows of A / out
constexpr int kK = 2 * kD;    // 2048 reduction dim
constexpr int kN = kD;        // 1024 output features

#define TILE_M 128
#define TILE_N 128
#define TILE_K 32

typedef __bf16 bf16x8 __attribute__((ext_vector_type(8)));
typedef float  f32x4  __attribute__((ext_vector_type(4)));

// round-to-nearest-even fp32 -> bf16, packed pair into one dword
__device__ __forceinline__ uint32_t pack_bf16x2(float a, float b) {
    uint32_t ua = __float_as_uint(a), ub = __float_as_uint(b);
    ua = (ua + 0x7fffu + ((ua >> 16) & 1u)) >> 16;
    ub = (ub + 0x7fffu + ((ub >> 16) & 1u)) >> 16;
    return ua | (ub << 16);
}

// C[m,n] = relu( sum_k A[m,k]*W[n,k] + bias[n] )
// A[m, k<1024]  = words[m*1024 + k]
// A[m, k>=1024] = smap[m]>=0 ? sents[(b*255+smap[m])*1024 + k-1024] : 0
__global__ __launch_bounds__(256)
void wsib_gemm(const float* __restrict__ words,
               const float* __restrict__ sents,
               const float* __restrict__ W,
               const float* __restrict__ bias,
               const int*   __restrict__ smap,
               float* __restrict__ out)
{
    // bf16 tiles stored as packed dwords: row stride = TILE_K/2 dwords (64B)
    __shared__ uint32_t Asm[TILE_M * TILE_K / 2];   // 8 KiB
    __shared__ uint32_t Bsm[TILE_N * TILE_K / 2];   // 8 KiB

    const int tid = threadIdx.x;
    const int nT  = blockIdx.x;   // 0..7   (fast: blocks sharing A rows adjacent)
    const int mT  = blockIdx.y;   // 0..255

    // ---- staging: each thread owns one (row, 16-float half) slice per k-step
    const int sRow = tid >> 1;          // 0..127
    const int half = tid & 1;           // which 16-float chunk of the 32-k tile
    const int mRow = mT * TILE_M + sRow;
    const int bIdx = mRow >> 12;        // / L (4096)
    const float* wsrc = words + (size_t)mRow * kD + half * 16;
    const int sidx = smap[mRow];
    const float* ssrc = (sidx >= 0)
        ? sents + ((size_t)bIdx * kS + sidx) * kD + half * 16
        : nullptr;
    const float* bsrc = W + (size_t)(nT * TILE_N + sRow) * kK + half * 16;
    uint32_t* adst = &Asm[sRow * (TILE_K / 2) + half * 8];
    uint32_t* bdst = &Bsm[sRow * (TILE_K / 2) + half * 8];

    // ---- compute: 4 waves in 2x2 grid, each wave 64x64 = 4x4 mfma 16x16 tiles
    const int lane = tid & 63;
    const int wv   = tid >> 6;
    const int wm   = (wv & 1) * 64;     // wave row offset in tile
    const int wn   = (wv >> 1) * 64;    // wave col offset in tile
    const int fr   = lane & 15;         // fragment row (m for A, n for B)
    const int quad = lane >> 4;         // k-quad: lane holds k = quad*8 + j

    f32x4 acc[4][4];
    #pragma unroll
    for (int i = 0; i < 4; ++i)
        #pragma unroll
        for (int j = 0; j < 4; ++j)
            acc[i][j] = (f32x4){0.f, 0.f, 0.f, 0.f};

    for (int k0 = 0; k0 < kK; k0 += TILE_K) {
        // ---- load + convert next tile into registers (overlaps prior MFMAs)
        uint32_t pa[8], pb[8];
        const float* asrc = (k0 < kD) ? (wsrc + k0)
                                      : (ssrc ? (ssrc + (k0 - kD)) : nullptr);
        if (asrc) {
            const float4* p = (const float4*)asrc;
            #pragma unroll
            for (int i = 0; i < 4; ++i) {
                float4 v = p[i];
                pa[2*i]   = pack_bf16x2(v.x, v.y);
                pa[2*i+1] = pack_bf16x2(v.z, v.w);
            }
        } else {
            #pragma unroll
            for (int i = 0; i < 8; ++i) pa[i] = 0u;
        }
        {
            const float4* p = (const float4*)(bsrc + k0);
            #pragma unroll
            for (int i = 0; i < 4; ++i) {
                float4 v = p[i];
                pb[2*i]   = pack_bf16x2(v.x, v.y);
                pb[2*i+1] = pack_bf16x2(v.z, v.w);
            }
        }

        __syncthreads();   // prev iter's fragment reads done before overwrite
        ((uint4*)adst)[0] = make_uint4(pa[0], pa[1], pa[2], pa[3]);
        ((uint4*)adst)[1] = make_uint4(pa[4], pa[5], pa[6], pa[7]);
        ((uint4*)bdst)[0] = make_uint4(pb[0], pb[1], pb[2], pb[3]);
        ((uint4*)bdst)[1] = make_uint4(pb[4], pb[5], pb[6], pb[7]);
        __syncthreads();   // tile visible

        // ---- fragments: 8x ds_read_b128
        bf16x8 af[4], bfv[4];
        #pragma unroll
        for (int mi = 0; mi < 4; ++mi) {
            int row = wm + mi * 16 + fr;
            af[mi] = *(const bf16x8*)&Asm[row * (TILE_K / 2) + quad * 4];
        }
        #pragma unroll
        for (int ni = 0; ni < 4; ++ni) {
            int row = wn + ni * 16 + fr;
            bfv[ni] = *(const bf16x8*)&Bsm[row * (TILE_K / 2) + quad * 4];
        }

        // ---- 16 MFMAs
        #pragma unroll
        for (int mi = 0; mi < 4; ++mi)
            #pragma unroll
            for (int ni = 0; ni < 4; ++ni)
                acc[mi][ni] = __builtin_amdgcn_mfma_f32_16x16x32_bf16(
                    af[mi], bfv[ni], acc[mi][ni], 0, 0, 0);
    }

    // ---- epilogue: bias + relu, fp32 store
    // C/D layout (verified m89): col = lane&15, row = quad*4 + r
    const int rowBase = mT * TILE_M + wm;
    const int colBase = nT * TILE_N + wn;
    float bv[4];
    #pragma unroll
    for (int ni = 0; ni < 4; ++ni) bv[ni] = bias[colBase + ni * 16 + fr];

    #pragma unroll
    for (int mi = 0; mi < 4; ++mi) {
        #pragma unroll
        for (int ni = 0; ni < 4; ++ni) {
            const int col = colBase + ni * 16 + fr;
            #pragma unroll
            for (int r = 0; r < 4; ++r) {
                const int row = rowBase + mi * 16 + quad * 4 + r;
                float v = acc[mi][ni][r] + bv[ni];
                out[(size_t)row * kN + col] = fmaxf(v, 0.f);
            }
        }
    }
}

extern "C" void kernel_launch(void* const* d_in, const int* in_sizes, int n_in,
                              void* d_out, int out_size, void* d_ws, size_t ws_size,
                              hipStream_t stream) {
    const float* words = (const float*)d_in[0];   // [8, 4096, 1024] f32
    const float* sents = (const float*)d_in[1];   // [8, 255, 1024]  f32
    const float* W     = (const float*)d_in[2];   // [1024, 2048]    f32
    const float* bias  = (const float*)d_in[3];   // [1024]          f32
    const int*   smap  = (const int*)d_in[4];     // [8, 4096]       i32
    float* out = (float*)d_out;                   // [8, 4096, 1024] f32

    dim3 grid(kN / TILE_N, kM / TILE_M);          // (8, 256)
    wsib_gemm<<<grid, 256, 0, stream>>>(words, sents, W, bias, smap, out);
}

// Round 2
// 529.593 us; speedup vs baseline: 1.0207x; 1.0207x over previous
//
#include <hip/hip_runtime.h>
#include <stdint.h>

// Problem constants (from reference): B=8, L=4096, D=1024, S=255
constexpr int kB = 8;
constexpr int kL = 4096;
constexpr int kD = 1024;
constexpr int kS = 255;
constexpr int kM = kB * kL;   // 32768 rows of A / out
constexpr int kK = 2 * kD;    // 2048 reduction dim
constexpr int kN = kD;        // 1024 output features

#define TILE_M 128
#define TILE_N 128
#define TILE_K 32
#define LDS_STRIDE 20   // dwords per row: 16 data + 4 pad (80B, 16B-aligned, kills 8-way conflicts)

typedef __bf16 bf16x8 __attribute__((ext_vector_type(8)));
typedef float  f32x4  __attribute__((ext_vector_type(4)));

// fp32 pair -> packed bf16x2, round-half-up (add 0x8000 then truncate via byte perm).
// 3 VALU ops vs 6 for full RNE; max extra error vs RNE is one tie-breaking ulp.
__device__ __forceinline__ uint32_t pk_bf16x2(float a, float b) {
    uint32_t ua = __float_as_uint(a) + 0x8000u;
    uint32_t ub = __float_as_uint(b) + 0x8000u;
    // dst = { hi16(ub), hi16(ua) }: src0 supplies bytes 7:4, src1 bytes 3:0
    return __builtin_amdgcn_perm(ub, ua, 0x07060302u);
}

// C[m,n] = relu( sum_k A[m,k]*W[n,k] + bias[n] )
// A[m, k<1024]  = words[m*1024 + k]
// A[m, k>=1024] = smap[m]>=0 ? sents[(b*255+smap[m])*1024 + k-1024] : 0
__global__ __launch_bounds__(256)
void wsib_gemm(const float* __restrict__ words,
               const float* __restrict__ sents,
               const float* __restrict__ W,
               const float* __restrict__ bias,
               const int*   __restrict__ smap,
               float* __restrict__ out)
{
    __shared__ uint32_t Asm[TILE_M * LDS_STRIDE];   // 10 KiB
    __shared__ uint32_t Bsm[TILE_N * LDS_STRIDE];   // 10 KiB

    const int tid = threadIdx.x;
    const int nT  = blockIdx.x;   // 0..7   (fast: blocks sharing A rows adjacent)
    const int mT  = blockIdx.y;   // 0..255

    // ---- staging: each thread owns one (row, 16-float half) slice per k-step
    const int sRow = tid >> 1;          // 0..127
    const int half = tid & 1;           // which 16-float chunk of the 32-k tile
    const int mRow = mT * TILE_M + sRow;
    const int bIdx = mRow >> 12;        // / L (4096)
    const float* wsrc = words + (size_t)mRow * kD + half * 16;
    const int sidx = smap[mRow];
    const float* ssrc = (sidx >= 0)
        ? sents + ((size_t)bIdx * kS + sidx) * kD + half * 16
        : nullptr;
    const float* bsrc = W + (size_t)(nT * TILE_N + sRow) * kK + half * 16;
    uint32_t* adst = &Asm[sRow * LDS_STRIDE + half * 8];
    uint32_t* bdst = &Bsm[sRow * LDS_STRIDE + half * 8];

    // ---- compute: 4 waves in 2x2 grid, each wave 64x64 = 4x4 mfma 16x16 tiles
    const int lane = tid & 63;
    const int wv   = tid >> 6;
    const int wm   = (wv & 1) * 64;     // wave row offset in tile
    const int wn   = (wv >> 1) * 64;    // wave col offset in tile
    const int fr   = lane & 15;         // fragment row (m for A, n for B)
    const int quad = lane >> 4;         // k-quad: lane holds k = quad*8 + j

    f32x4 acc[4][4];
    #pragma unroll
    for (int i = 0; i < 4; ++i)
        #pragma unroll
        for (int j = 0; j < 4; ++j)
            acc[i][j] = (f32x4){0.f, 0.f, 0.f, 0.f};

    // ---- prologue: prefetch tile 0 into registers (k0=0 is always words-side)
    float4 ra[4], rb[4];
    {
        const float4* pa = (const float4*)wsrc;
        const float4* pb = (const float4*)bsrc;
        #pragma unroll
        for (int i = 0; i < 4; ++i) { ra[i] = pa[i]; rb[i] = pb[i]; }
    }

    for (int k0 = 0; k0 < kK; k0 += TILE_K) {
        // ---- convert prefetched regs (vmcnt wait lands here, one stage late)
        uint32_t pa[8], pb[8];
        #pragma unroll
        for (int i = 0; i < 4; ++i) {
            pa[2*i]   = pk_bf16x2(ra[i].x, ra[i].y);
            pa[2*i+1] = pk_bf16x2(ra[i].z, ra[i].w);
            pb[2*i]   = pk_bf16x2(rb[i].x, rb[i].y);
            pb[2*i+1] = pk_bf16x2(rb[i].z, rb[i].w);
        }

        __syncthreads();   // prev iter's fragment reads done before overwrite
        ((uint4*)adst)[0] = make_uint4(pa[0], pa[1], pa[2], pa[3]);
        ((uint4*)adst)[1] = make_uint4(pa[4], pa[5], pa[6], pa[7]);
        ((uint4*)bdst)[0] = make_uint4(pb[0], pb[1], pb[2], pb[3]);
        ((uint4*)bdst)[1] = make_uint4(pb[4], pb[5], pb[6], pb[7]);
        __syncthreads();   // tile visible

        // ---- issue next tile's prefetch (in flight across the MFMA stage)
        const int k1 = k0 + TILE_K;
        if (k1 < kK) {
            const float* asrc = (k1 < kD) ? (wsrc + k1)
                                          : (ssrc ? (ssrc + (k1 - kD)) : nullptr);
            if (asrc) {
                const float4* p = (const float4*)asrc;
                #pragma unroll
                for (int i = 0; i < 4; ++i) ra[i] = p[i];
            } else {
                #pragma unroll
                for (int i = 0; i < 4; ++i) ra[i] = make_float4(0.f, 0.f, 0.f, 0.f);
            }
            const float4* p = (const float4*)(bsrc + k1);
            #pragma unroll
            for (int i = 0; i < 4; ++i) rb[i] = p[i];
        }

        // ---- fragments: 8x ds_read_b128 (stride 20 dwords: only free 2-way aliasing)
        bf16x8 af[4], bfv[4];
        #pragma unroll
        for (int mi = 0; mi < 4; ++mi) {
            int row = wm + mi * 16 + fr;
            af[mi] = *(const bf16x8*)&Asm[row * LDS_STRIDE + quad * 4];
        }
        #pragma unroll
        for (int ni = 0; ni < 4; ++ni) {
            int row = wn + ni * 16 + fr;
            bfv[ni] = *(const bf16x8*)&Bsm[row * LDS_STRIDE + quad * 4];
        }

        // ---- 16 MFMAs
        #pragma unroll
        for (int mi = 0; mi < 4; ++mi)
            #pragma unroll
            for (int ni = 0; ni < 4; ++ni)
                acc[mi][ni] = __builtin_amdgcn_mfma_f32_16x16x32_bf16(
                    af[mi], bfv[ni], acc[mi][ni], 0, 0, 0);
    }

    // ---- epilogue: bias + relu, fp32 store
    // C/D layout (verified m89): col = lane&15, row = quad*4 + r
    const int rowBase = mT * TILE_M + wm;
    const int colBase = nT * TILE_N + wn;
    float bv[4];
    #pragma unroll
    for (int ni = 0; ni < 4; ++ni) bv[ni] = bias[colBase + ni * 16 + fr];

    #pragma unroll
    for (int mi = 0; mi < 4; ++mi) {
        #pragma unroll
        for (int ni = 0; ni < 4; ++ni) {
            const int col = colBase + ni * 16 + fr;
            #pragma unroll
            for (int r = 0; r < 4; ++r) {
                const int row = rowBase + mi * 16 + quad * 4 + r;
                float v = acc[mi][ni][r] + bv[ni];
                out[(size_t)row * kN + col] = fmaxf(v, 0.f);
            }
        }
    }
}

extern "C" void kernel_launch(void* const* d_in, const int* in_sizes, int n_in,
                              void* d_out, int out_size, void* d_ws, size_t ws_size,
                              hipStream_t stream) {
    const float* words = (const float*)d_in[0];   // [8, 4096, 1024] f32
    const float* sents = (const float*)d_in[1];   // [8, 255, 1024]  f32
    const float* W     = (const float*)d_in[2];   // [1024, 2048]    f32
    const float* bias  = (const float*)d_in[3];   // [1024]          f32
    const int*   smap  = (const int*)d_in[4];     // [8, 4096]       i32
    float* out = (float*)d_out;                   // [8, 4096, 1024] f32

    dim3 grid(kN / TILE_N, kM / TILE_M);          // (8, 256)
    wsib_gemm<<<grid, 256, 0, stream>>>(words, sents, W, bias, smap, out);
}